// Round 9
// baseline (120.859 us; speedup 1.0000x reference)
//
#include <hip/hip_runtime.h>

static constexpr int CH   = 128;   // CHANNELS
static constexpr int KW   = 160;   // W row length (bf16): 128 tok + wc0,wc1,b1 + pad
static constexpr int KPAD = 192;   // Atile row length (bf16) -> 384B rows

typedef __attribute__((ext_vector_type(8))) short bf16x8;
typedef __attribute__((ext_vector_type(4))) float f32x4;

__device__ inline unsigned short f2bf(float x) {
    unsigned int u = __float_as_uint(x);
    unsigned int r = (u + 0x7fffu + ((u >> 16) & 1u)) >> 16;  // RNE
    return (unsigned short)r;
}
__device__ inline unsigned int pack2bf(float a, float b) {
    return (unsigned int)f2bf(a) | ((unsigned int)f2bf(b) << 16);
}
__device__ inline float bf2f(unsigned short v) {
    return __uint_as_float((unsigned int)v << 16);
}

// ---------------------------------------------------------------------------
// idxp[e] = src | (dst<<16).  is64 detection inlined (each block redundantly
// checks high words of the first 128 elements; all-zero => int64).
// ---------------------------------------------------------------------------
__global__ __launch_bounds__(256) void idx_prep(
    const unsigned int* __restrict__ idxw, unsigned int* __restrict__ idxp,
    int E) {
    unsigned nz = 0;
    const int lane = threadIdx.x & 63;
    for (int i = lane; i < 128; i += 64) nz |= idxw[2 * i + 1];
    const int is64 = (__ballot(nz != 0u) == 0ULL) ? 1 : 0;
    const int stride = gridDim.x * 256;
    for (int i = blockIdx.x * 256 + threadIdx.x; i < E; i += stride) {
        const unsigned s = is64 ? idxw[2 * i] : idxw[i];
        const unsigned d = is64 ? idxw[2 * (E + i)] : idxw[E + i];
        idxp[i] = s | (d << 16);
    }
}

// ---------------------------------------------------------------------------
// W[c][k] (bf16, [256][KW]): k<128 tok-weights; k=128/129 = +-wc0/wc1;
// k=130 = b1 (Q only); rest 0.
// ---------------------------------------------------------------------------
__global__ __launch_bounds__(192) void w1_prep(const float* __restrict__ w1,
                                               const float* __restrict__ b1,
                                               unsigned short* __restrict__ W) {
    const int c = blockIdx.x;    // 0..255
    const int k = threadIdx.x;
    if (k >= KW) return;
    const bool isQ = c >= 128;
    const int cc = c & 127;
    float v;
    if (k < 128)       v = isQ ? w1[(size_t)(128 + k) * CH + cc]
                               : w1[(size_t)k * CH + cc];
    else if (k == 128) v = (isQ ? 1.f : -1.f) * w1[(size_t)(2 * CH) * CH + cc];
    else if (k == 129) v = (isQ ? 1.f : -1.f) * w1[(size_t)(2 * CH + 1) * CH + cc];
    else if (k == 130) v = isQ ? b1[cc] : 0.f;
    else               v = 0.f;
    W[(size_t)c * KW + k] = f2bf(v);
}

// ---------------------------------------------------------------------------
// Node stage: 32 nodes x 256 cols per block, swapped-operand MFMA, K=160
// (coords+bias folded). Stores P/Q in CHUNKED layout:
//   Pc[(chunk*N + node)*16 + (c&15)], chunk = c>>4  (same for Qc).
// ---------------------------------------------------------------------------
__global__ __launch_bounds__(256) void node_mfma3(
    const float* __restrict__ tokens, const float* __restrict__ coords,
    const unsigned short* __restrict__ W, unsigned short* __restrict__ Pc,
    unsigned short* __restrict__ Qc, int N) {
    __shared__ unsigned short Atile[32 * KPAD];  // 12 KB, XOR-swizzled rows

    const int t    = threadIdx.x;
    const int l    = t & 63;
    const int wid  = t >> 6;
    const int n0   = blockIdx.x * 32;
    const int woff = wid * 64;
    const int bl   = l & 15;
    const int bh   = l >> 4;

    // token chunks: 32 nodes x 16 chunks of 16B
#pragma unroll
    for (int it = 0; it < 2; ++it) {
        const int idx  = it * 256 + t;
        const int node = idx >> 4;
        const int cq   = idx & 15;
        float4 v0 = make_float4(0.f, 0.f, 0.f, 0.f);
        float4 v1 = v0;
        if (n0 + node < N) {
            const float* src = &tokens[(size_t)(n0 + node) * CH + cq * 8];
            v0 = *(const float4*)src;
            v1 = *(const float4*)(src + 4);
        }
        uint4 u;
        u.x = pack2bf(v0.x, v0.y);
        u.y = pack2bf(v0.z, v0.w);
        u.z = pack2bf(v1.x, v1.y);
        u.w = pack2bf(v1.z, v1.w);
        const int byte = node * 384 + ((cq * 16) ^ ((node & 7) << 4));
        *(uint4*)((char*)Atile + byte) = u;
    }
    // ext chunks: k=128..191 -> (cx, cy, 1, 0, ...)
    {
        const int node = t >> 3;
        const int ce   = t & 7;
        uint4 u = make_uint4(0u, 0u, 0u, 0u);
        if (ce == 0 && n0 + node < N) {
            const float cx = coords[2 * (n0 + node)];
            const float cy = coords[2 * (n0 + node) + 1];
            u.x = pack2bf(cx, cy);
            u.y = pack2bf(1.f, 0.f);
        }
        const int byte = node * 384 + (((16 + ce) * 16) ^ ((node & 7) << 4));
        *(uint4*)((char*)Atile + byte) = u;
    }
    __syncthreads();

    f32x4 acc[4][2];
#pragma unroll
    for (int m = 0; m < 4; ++m)
#pragma unroll
        for (int n = 0; n < 2; ++n) acc[m][n] = (f32x4){0.f, 0.f, 0.f, 0.f};

#pragma unroll
    for (int ks = 0; ks < 5; ++ks) {
        bf16x8 wfrag[4], tfrag[2];
#pragma unroll
        for (int m = 0; m < 4; ++m)
            wfrag[m] = *(const bf16x8*)&W[(size_t)(woff + m * 16 + bl) * KW +
                                          ks * 32 + bh * 8];
#pragma unroll
        for (int n = 0; n < 2; ++n) {
            const int row  = n * 16 + bl;
            const int byte = row * 384 + ((ks * 64 + bh * 16) ^ ((row & 7) << 4));
            tfrag[n] = *(const bf16x8*)((const char*)Atile + byte);
        }
#pragma unroll
        for (int m = 0; m < 4; ++m)
#pragma unroll
            for (int n = 0; n < 2; ++n)
                acc[m][n] = __builtin_amdgcn_mfma_f32_16x16x32_bf16(
                    wfrag[m], tfrag[n], acc[m][n], 0, 0, 0);
    }

#pragma unroll
    for (int m = 0; m < 4; ++m) {
        const int c = woff + m * 16 + bh * 4;    // output col 0..255
        const int cc = c & (CH - 1);
        unsigned short* base = (c < CH ? Pc : Qc) +
                               (size_t)(cc >> 4) * N * 16 + (cc & 15);
#pragma unroll
        for (int n = 0; n < 2; ++n) {
            const int node = n0 + n * 16 + bl;
            if (node < N) {
                uint2 val;
                val.x = pack2bf(acc[m][n][0], acc[m][n][1]);
                val.y = pack2bf(acc[m][n][2], acc[m][n][3]);
                *(uint2*)&base[(size_t)node * 16] = val;
            }
        }
    }
}

// ---------------------------------------------------------------------------
// Channel-chunked edge partials, COALESCED: 4 lanes per edge, each lane loads
// uint2 (8B = 4 ch) of the 32B row -> all 4 lanes hit ONE 64B line -> the TA
// merges them into a single L2 request (vs 4 divergent requests in v8).
// chunk = blockIdx%8 (XCD round-robin pin); working set 3.2 MB -> L2-hit.
// ---------------------------------------------------------------------------
template <typename PT>
__global__ __launch_bounds__(256) void edge_partial2(
    const unsigned int* __restrict__ idxp, const unsigned short* __restrict__ Pc,
    const unsigned short* __restrict__ Qc, const float* __restrict__ w2,
    PT* __restrict__ partial, int N, int E) {
    const int chunk = blockIdx.x & 7;
    const int t    = threadIdx.x;
    const int sub  = t & 3;    // channel quad (4 ch) within the 16-ch chunk
    const int eoff = t >> 2;   // edge slot within block: 0..63
    const float4 w = *(const float4*)&w2[chunk * 16 + sub * 4];
    const unsigned short* Pb = Pc + (size_t)chunk * N * 16;
    const unsigned short* Qb = Qc + (size_t)chunk * N * 16;
    PT* po = partial + (size_t)chunk * E;

    const int base0  = (int)(blockIdx.x >> 3) * 256;
    const int stride = (int)(gridDim.x >> 3) * 256;

    for (int base = base0; base < E; base += stride) {
        int e[4];
        unsigned pk[4];
        bool ok[4];
#pragma unroll
        for (int j = 0; j < 4; ++j) {
            e[j]  = base + eoff + 64 * j;
            ok[j] = e[j] < E;
            pk[j] = ok[j] ? __builtin_nontemporal_load(&idxp[e[j]]) : 0u;
        }
        uint2 pv[4], qv[4];
#pragma unroll
        for (int j = 0; j < 4; ++j)
            pv[j] = *(const uint2*)(Pb + (size_t)(pk[j] & 0xffffu) * 16 + sub * 4);
#pragma unroll
        for (int j = 0; j < 4; ++j)
            qv[j] = *(const uint2*)(Qb + (size_t)(pk[j] >> 16) * 16 + sub * 4);

#pragma unroll
        for (int j = 0; j < 4; ++j) {
            const float p0 = __uint_as_float(pv[j].x << 16);
            const float p1 = __uint_as_float(pv[j].x & 0xffff0000u);
            const float p2 = __uint_as_float(pv[j].y << 16);
            const float p3 = __uint_as_float(pv[j].y & 0xffff0000u);
            const float q0 = __uint_as_float(qv[j].x << 16);
            const float q1 = __uint_as_float(qv[j].x & 0xffff0000u);
            const float q2 = __uint_as_float(qv[j].y << 16);
            const float q3 = __uint_as_float(qv[j].y & 0xffff0000u);
            float acc = fmaxf(p0 + q0, 0.f) * w.x;
            acc = fmaf(fmaxf(p1 + q1, 0.f), w.y, acc);
            acc = fmaf(fmaxf(p2 + q2, 0.f), w.z, acc);
            acc = fmaf(fmaxf(p3 + q3, 0.f), w.w, acc);
            // 4-lane reduce: all lanes of the quad end with the edge sum
            acc += __shfl_xor(acc, 1);
            acc += __shfl_xor(acc, 2);
            if (sub == 0 && ok[j]) {
                if constexpr (sizeof(PT) == 2)
                    __builtin_nontemporal_store(f2bf(acc), &po[e[j]]);
                else
                    __builtin_nontemporal_store(acc, &po[e[j]]);
            }
        }
    }
}

// ---------------------------------------------------------------------------
// out[e] = sum_c partial[c][e] + b2.  Thread per 4 edges (float4 store).
// ---------------------------------------------------------------------------
template <typename PT>
__global__ __launch_bounds__(256) void edge_reduce(
    const PT* __restrict__ partial, const float* __restrict__ b2,
    float* __restrict__ out, int E) {
    const int nq = E >> 2;
    const float bias = b2[0];
    const int stride = gridDim.x * 256;
    for (int q = blockIdx.x * 256 + threadIdx.x; q < nq; q += stride) {
        const int e = q * 4;
        float s0 = bias, s1 = bias, s2 = bias, s3 = bias;
#pragma unroll
        for (int c = 0; c < 8; ++c) {
            if constexpr (sizeof(PT) == 2) {
                const ushort4 v = *(const ushort4*)&partial[(size_t)c * E + e];
                s0 += bf2f(v.x); s1 += bf2f(v.y); s2 += bf2f(v.z); s3 += bf2f(v.w);
            } else {
                const float4 v = *(const float4*)&partial[(size_t)c * E + e];
                s0 += v.x; s1 += v.y; s2 += v.z; s3 += v.w;
            }
        }
        *(float4*)&out[e] = make_float4(s0, s1, s2, s3);
    }
    // tail (E not multiple of 4)
    if (blockIdx.x == 0 && threadIdx.x < (E & 3)) {
        const int e = (E & ~3) + threadIdx.x;
        float s = bias;
#pragma unroll
        for (int c = 0; c < 8; ++c) {
            if constexpr (sizeof(PT) == 2) s += bf2f(partial[(size_t)c * E + e]);
            else                           s += partial[(size_t)c * E + e];
        }
        out[e] = s;
    }
}

extern "C" void kernel_launch(void* const* d_in, const int* in_sizes, int n_in,
                              void* d_out, int out_size, void* d_ws,
                              size_t ws_size, hipStream_t stream) {
    const float* tokens = (const float*)d_in[0];
    const float* coords = (const float*)d_in[1];
    const unsigned int* idxw = (const unsigned int*)d_in[2];
    const float* w1 = (const float*)d_in[3];
    const float* b1 = (const float*)d_in[4];
    const float* w2 = (const float*)d_in[5];
    const float* b2 = (const float*)d_in[6];
    float* out = (float*)d_out;

    const int N = in_sizes[0] / CH;       // 50000
    const int E = (int)(in_sizes[2] / 2); // 800000

    unsigned short* Pc = (unsigned short*)d_ws;
    unsigned short* Qc = Pc + (size_t)N * CH;
    unsigned int* idxp = (unsigned int*)(Qc + (size_t)N * CH);
    unsigned short* W = (unsigned short*)(idxp + E);
    char* pbase = (char*)(W + 256 * KW);
    const size_t used = (size_t)(pbase - (char*)d_ws);
    const bool pf32 = (used + (size_t)8 * E * sizeof(float)) <= ws_size;

    idx_prep<<<1024, 256, 0, stream>>>(idxw, idxp, E);
    w1_prep<<<256, 192, 0, stream>>>(w1, b1, W);

    node_mfma3<<<(N + 31) / 32, 256, 0, stream>>>(tokens, coords, W, Pc, Qc, N);

    if (pf32) {
        float* partial = (float*)pbase;
        edge_partial2<float><<<2048, 256, 0, stream>>>(idxp, Pc, Qc, w2,
                                                       partial, N, E);
        edge_reduce<float><<<784, 256, 0, stream>>>(partial, b2, out, E);
    } else {
        unsigned short* partial = (unsigned short*)pbase;
        edge_partial2<unsigned short><<<2048, 256, 0, stream>>>(idxp, Pc, Qc, w2,
                                                                partial, N, E);
        edge_reduce<unsigned short><<<784, 256, 0, stream>>>(partial, b2, out, E);
    }
}

// Round 10
// 81.587 us; speedup vs baseline: 1.4813x; 1.4813x over previous
//
#include <hip/hip_runtime.h>

static constexpr int CH   = 128;   // CHANNELS
static constexpr int KPAD = 192;   // Atile row length (bf16) -> 384B rows

typedef __attribute__((ext_vector_type(8))) short bf16x8;
typedef __attribute__((ext_vector_type(4))) float f32x4;
typedef __attribute__((ext_vector_type(4))) unsigned int u32x4;

__device__ inline unsigned short f2bf(float x) {
    unsigned int u = __float_as_uint(x);
    unsigned int r = (u + 0x7fffu + ((u >> 16) & 1u)) >> 16;  // RNE
    return (unsigned short)r;
}
__device__ inline unsigned int pack2bf(float a, float b) {
    return (unsigned int)f2bf(a) | ((unsigned int)f2bf(b) << 16);
}

// ---------------------------------------------------------------------------
// idx2[e] = { src_byte_off, dst_byte_off } (row = 256B). Pads to Epad with 0.
// is64 detection fused (high words of first 128 elements all zero => int64).
// ---------------------------------------------------------------------------
__global__ __launch_bounds__(256) void idx_prep(
    const unsigned int* __restrict__ idxw, uint2* __restrict__ idx2,
    long long E, long long Epad) {
    unsigned nz = 0;
    const int lane = threadIdx.x & 63;
    for (int i = lane; i < 128; i += 64) nz |= idxw[2 * i + 1];
    const int is64 = (__ballot(nz != 0u) == 0ULL) ? 1 : 0;
    const long long stride = (long long)gridDim.x * blockDim.x;
    for (long long i = (long long)blockIdx.x * blockDim.x + threadIdx.x;
         i < Epad; i += stride) {
        uint2 v = make_uint2(0u, 0u);
        if (i < E) {
            const unsigned s = is64 ? idxw[2 * i] : idxw[i];
            const unsigned d = is64 ? idxw[2 * (E + i)] : idxw[E + i];
            v = make_uint2(s << 8, d << 8);
        }
        idx2[i] = v;
    }
}

// ---------------------------------------------------------------------------
// Wf: fragment-linear weight layout. Logical W_col[c][k]:
//   k<128 : c<128 ? w1[k][c] : w1[128+k][c-128]
//   k=128 : +-w1[256][cc]  (-: P, +: Q)   k=129 : +-w1[257][cc]
//   k=130 : b1 (Q only)                   k>130 : 0
// Physical: seg = (wave*5 + ks)*4 + m; lane l holds 8 bf16 at
//   Wf[seg*512 + l*8]  =  W_col[wave*64 + m*16 + (l&15)][ks*32 + (l>>4)*8 ..+8]
// -> each wfrag load in the node kernel is one dense 1KB wave instruction.
// ---------------------------------------------------------------------------
__global__ __launch_bounds__(256) void w1_prep2(const float* __restrict__ w1,
                                                const float* __restrict__ b1,
                                                unsigned short* __restrict__ Wf) {
    const int gid = blockIdx.x * 256 + threadIdx.x;  // 0..5119
    if (gid >= 4 * 5 * 4 * 64) return;
    const int lane = gid & 63;
    const int seg  = gid >> 6;
    const int m    = seg & 3;
    const int ks   = (seg >> 2) % 5;
    const int w    = seg / 20;
    const int c    = w * 64 + m * 16 + (lane & 15);
    const int k0   = ks * 32 + (lane >> 4) * 8;
    const bool isQ = c >= 128;
    const int cc   = c & 127;
    const float sgn = isQ ? 1.f : -1.f;
    unsigned int out[4];
#pragma unroll
    for (int h = 0; h < 4; ++h) {
        float v[2];
#pragma unroll
        for (int j = 0; j < 2; ++j) {
            const int k = k0 + 2 * h + j;
            float x;
            if (k < 128)       x = isQ ? w1[(size_t)(128 + k) * CH + cc]
                                       : w1[(size_t)k * CH + cc];
            else if (k == 128) x = sgn * w1[(size_t)(2 * CH) * CH + cc];
            else if (k == 129) x = sgn * w1[(size_t)(2 * CH + 1) * CH + cc];
            else if (k == 130) x = isQ ? b1[cc] : 0.f;
            else               x = 0.f;
            v[j] = x;
        }
        out[h] = pack2bf(v[0], v[1]);
    }
    *(uint4*)&Wf[(size_t)gid * 8] = make_uint4(out[0], out[1], out[2], out[3]);
}

// ---------------------------------------------------------------------------
// Node stage: 32 nodes x 256 cols per block, swapped-operand MFMA, K=160
// (coords+bias folded). wfrag loads from fragment-linear Wf (dense 1KB/instr,
// L1-resident across blocks). Row-major bf16 stores to Pb/Qb (8B packed).
// ---------------------------------------------------------------------------
__global__ __launch_bounds__(256) void node_mfma4(
    const float* __restrict__ tokens, const float* __restrict__ coords,
    const unsigned short* __restrict__ Wf, unsigned short* __restrict__ Pb,
    unsigned short* __restrict__ Qb, int N) {
    __shared__ unsigned short Atile[32 * KPAD];  // 12 KB, XOR-swizzled rows

    const int t    = threadIdx.x;
    const int l    = t & 63;
    const int wid  = t >> 6;
    const int n0   = blockIdx.x * 32;
    const int woff = wid * 64;
    const int bl   = l & 15;
    const int bh   = l >> 4;

    // token chunks: 32 nodes x 16 chunks of 16B
#pragma unroll
    for (int it = 0; it < 2; ++it) {
        const int idx  = it * 256 + t;
        const int node = idx >> 4;
        const int cq   = idx & 15;
        float4 v0 = make_float4(0.f, 0.f, 0.f, 0.f);
        float4 v1 = v0;
        if (n0 + node < N) {
            const float* src = &tokens[(size_t)(n0 + node) * CH + cq * 8];
            v0 = *(const float4*)src;
            v1 = *(const float4*)(src + 4);
        }
        uint4 u;
        u.x = pack2bf(v0.x, v0.y);
        u.y = pack2bf(v0.z, v0.w);
        u.z = pack2bf(v1.x, v1.y);
        u.w = pack2bf(v1.z, v1.w);
        const int byte = node * 384 + ((cq * 16) ^ ((node & 7) << 4));
        *(uint4*)((char*)Atile + byte) = u;
    }
    // ext chunks: k=128..191 -> (cx, cy, 1, 0, ...)
    {
        const int node = t >> 3;
        const int ce   = t & 7;
        uint4 u = make_uint4(0u, 0u, 0u, 0u);
        if (ce == 0 && n0 + node < N) {
            const float cx = coords[2 * (n0 + node)];
            const float cy = coords[2 * (n0 + node) + 1];
            u.x = pack2bf(cx, cy);
            u.y = pack2bf(1.f, 0.f);
        }
        const int byte = node * 384 + (((16 + ce) * 16) ^ ((node & 7) << 4));
        *(uint4*)((char*)Atile + byte) = u;
    }
    __syncthreads();

    f32x4 acc[4][2];
#pragma unroll
    for (int m = 0; m < 4; ++m)
#pragma unroll
        for (int n = 0; n < 2; ++n) acc[m][n] = (f32x4){0.f, 0.f, 0.f, 0.f};

#pragma unroll
    for (int ks = 0; ks < 5; ++ks) {
        bf16x8 wfrag[4], tfrag[2];
#pragma unroll
        for (int m = 0; m < 4; ++m)
            wfrag[m] = *(const bf16x8*)&Wf[(size_t)(((wid * 5 + ks) * 4 + m) * 64
                                                    + l) * 8];
#pragma unroll
        for (int n = 0; n < 2; ++n) {
            const int row  = n * 16 + bl;
            const int byte = row * 384 + ((ks * 64 + bh * 16) ^ ((row & 7) << 4));
            tfrag[n] = *(const bf16x8*)((const char*)Atile + byte);
        }
#pragma unroll
        for (int m = 0; m < 4; ++m)
#pragma unroll
            for (int n = 0; n < 2; ++n)
                acc[m][n] = __builtin_amdgcn_mfma_f32_16x16x32_bf16(
                    wfrag[m], tfrag[n], acc[m][n], 0, 0, 0);
    }

    // row-major stores: D rows = output cols; 4 acc regs = 4 consecutive cols
#pragma unroll
    for (int m = 0; m < 4; ++m) {
        const int c  = woff + m * 16 + bh * 4;   // output col 0..255
        const int cc = c & (CH - 1);
        unsigned short* dst = (c < CH) ? Pb : Qb;
#pragma unroll
        for (int n = 0; n < 2; ++n) {
            const int node = n0 + n * 16 + bl;
            if (node < N) {
                uint2 val;
                val.x = pack2bf(acc[m][n][0], acc[m][n][1]);
                val.y = pack2bf(acc[m][n][2], acc[m][n][3]);
                *(uint2*)&dst[(size_t)node * CH + cc] = val;
            }
        }
    }
}

// ---------------------------------------------------------------------------
// Edge kernel (round-7 proven): 16-lane group owns EIGHT edges/iter (16
// outstanding row gathers); lane covers 8 channels (16B).
//   out[e] = dot(relu(P[src] + Q[dst]), w2) + b2
// idx loads nontemporal so they don't evict P/Q from L2.
// ---------------------------------------------------------------------------
__global__ __launch_bounds__(256) void edge_g16x8(
    const unsigned int* __restrict__ idx2, const char* __restrict__ Pb,
    const char* __restrict__ Qb, const float* __restrict__ w2,
    const float* __restrict__ b2, float* __restrict__ out, long long E) {
    const int t  = threadIdx.x;
    const int gl = t & 15;
    const long long nch = (E + 7) >> 3;  // 8-edge chunks
    const long long g0  = (long long)blockIdx.x * 16 + (t >> 4);
    const long long ng  = (long long)gridDim.x * 16;
    const float4 w2a = *(const float4*)&w2[8 * gl];
    const float4 w2b = *(const float4*)&w2[8 * gl + 4];
    const float bias = b2[0];

    for (long long chk = g0; chk < nch; chk += ng) {
        const long long e0 = chk << 3;
        const u32x4* ip = (const u32x4*)&idx2[e0 * 2];  // 64B, aligned
        const u32x4 i0 = __builtin_nontemporal_load(ip);
        const u32x4 i1 = __builtin_nontemporal_load(ip + 1);
        const u32x4 i2 = __builtin_nontemporal_load(ip + 2);
        const u32x4 i3 = __builtin_nontemporal_load(ip + 3);
        const unsigned soff[8] = {i0.x, i0.z, i1.x, i1.z, i2.x, i2.z, i3.x, i3.z};
        const unsigned doff[8] = {i0.y, i0.w, i1.y, i1.w, i2.y, i2.w, i3.y, i3.w};
        uint4 pv[8], qv[8];
#pragma unroll
        for (int j = 0; j < 8; ++j)
            pv[j] = *(const uint4*)(Pb + soff[j] + 16 * gl);
#pragma unroll
        for (int j = 0; j < 8; ++j)
            qv[j] = *(const uint4*)(Qb + doff[j] + 16 * gl);

        float part[8];
#pragma unroll
        for (int j = 0; j < 8; ++j) {
            float acc = 0.f;
            const unsigned pw[4] = {pv[j].x, pv[j].y, pv[j].z, pv[j].w};
            const unsigned qw[4] = {qv[j].x, qv[j].y, qv[j].z, qv[j].w};
            const float wv[8] = {w2a.x, w2a.y, w2a.z, w2a.w,
                                 w2b.x, w2b.y, w2b.z, w2b.w};
#pragma unroll
            for (int wdx = 0; wdx < 4; ++wdx) {
                const float plo = __uint_as_float(pw[wdx] << 16);
                const float phi = __uint_as_float(pw[wdx] & 0xffff0000u);
                const float qlo = __uint_as_float(qw[wdx] << 16);
                const float qhi = __uint_as_float(qw[wdx] & 0xffff0000u);
                const float hlo = fmaxf(plo + qlo, 0.f);
                const float hhi = fmaxf(phi + qhi, 0.f);
                acc = fmaf(hlo, wv[2 * wdx], acc);
                acc = fmaf(hhi, wv[2 * wdx + 1], acc);
            }
            part[j] = acc;
        }

        // butterfly with packing: lane (gl&7)=j ends holding edge j's sum
        float t0 = part[0] + __shfl_xor(part[0], 1);
        float t1 = part[1] + __shfl_xor(part[1], 1);
        float t2 = part[2] + __shfl_xor(part[2], 1);
        float t3 = part[3] + __shfl_xor(part[3], 1);
        float t4 = part[4] + __shfl_xor(part[4], 1);
        float t5 = part[5] + __shfl_xor(part[5], 1);
        float t6 = part[6] + __shfl_xor(part[6], 1);
        float t7 = part[7] + __shfl_xor(part[7], 1);
        float a0 = (gl & 1) ? t1 : t0;
        float a1 = (gl & 1) ? t3 : t2;
        float a2 = (gl & 1) ? t5 : t4;
        float a3 = (gl & 1) ? t7 : t6;
        a0 += __shfl_xor(a0, 2);
        a1 += __shfl_xor(a1, 2);
        a2 += __shfl_xor(a2, 2);
        a3 += __shfl_xor(a3, 2);
        float b0  = (gl & 2) ? a1 : a0;
        float b1v = (gl & 2) ? a3 : a2;
        b0  += __shfl_xor(b0, 4);
        b1v += __shfl_xor(b1v, 4);
        float c = (gl & 4) ? b1v : b0;
        c += __shfl_xor(c, 8);

        if (gl < 8 && e0 + gl < E) out[e0 + gl] = c + bias;
    }
}

extern "C" void kernel_launch(void* const* d_in, const int* in_sizes, int n_in,
                              void* d_out, int out_size, void* d_ws,
                              size_t ws_size, hipStream_t stream) {
    const float* tokens = (const float*)d_in[0];
    const float* coords = (const float*)d_in[1];
    const unsigned int* idxw = (const unsigned int*)d_in[2];
    const float* w1 = (const float*)d_in[3];
    const float* b1 = (const float*)d_in[4];
    const float* w2 = (const float*)d_in[5];
    const float* b2 = (const float*)d_in[6];
    float* out = (float*)d_out;

    const int N = in_sizes[0] / CH;       // 50000
    const long long E = in_sizes[2] / 2;  // 800000
    const long long Epad = ((E + 7) >> 3) << 3;

    unsigned short* Pb = (unsigned short*)d_ws;
    unsigned short* Qb = Pb + (size_t)N * CH;
    uint2* idx2 = (uint2*)(Qb + (size_t)N * CH);
    unsigned short* Wf = (unsigned short*)(idx2 + Epad);  // 80 KB

    idx_prep<<<1024, 256, 0, stream>>>(idxw, idx2, E, Epad);
    w1_prep2<<<20, 256, 0, stream>>>(w1, b1, Wf);

    node_mfma4<<<(N + 31) / 32, 256, 0, stream>>>(tokens, coords, Wf, Pb, Qb, N);

    edge_g16x8<<<2048, 256, 0, stream>>>((const unsigned int*)idx2,
                                         (const char*)Pb, (const char*)Qb,
                                         w2, b2, out, E);
}

// Round 12
// 77.449 us; speedup vs baseline: 1.5605x; 1.0534x over previous
//
#include <hip/hip_runtime.h>

static constexpr int CH   = 128;   // CHANNELS
static constexpr int KPAD = 192;   // Atile row length (bf16) -> 384B rows

typedef __attribute__((ext_vector_type(8))) short bf16x8;
typedef __attribute__((ext_vector_type(4))) float f32x4;
typedef __attribute__((ext_vector_type(2))) unsigned int u32x2;

__device__ inline unsigned short f2bf(float x) {
    unsigned int u = __float_as_uint(x);
    unsigned int r = (u + 0x7fffu + ((u >> 16) & 1u)) >> 16;  // RNE
    return (unsigned short)r;
}
__device__ inline unsigned int pack2bf(float a, float b) {
    return (unsigned int)f2bf(a) | ((unsigned int)f2bf(b) << 16);
}

// ---------------------------------------------------------------------------
// idx2[e] = { src*128, dst*128 } byte offsets (half-rows = 128B).
// is64 detection fused (high words of first 128 elements all zero => int64).
// ---------------------------------------------------------------------------
__global__ __launch_bounds__(256) void idx_prep(
    const unsigned int* __restrict__ idxw, uint2* __restrict__ idx2,
    long long E, long long Epad) {
    unsigned nz = 0;
    const int lane = threadIdx.x & 63;
    for (int i = lane; i < 128; i += 64) nz |= idxw[2 * i + 1];
    const int is64 = (__ballot(nz != 0u) == 0ULL) ? 1 : 0;
    const long long stride = (long long)gridDim.x * blockDim.x;
    for (long long i = (long long)blockIdx.x * blockDim.x + threadIdx.x;
         i < Epad; i += stride) {
        uint2 v = make_uint2(0u, 0u);
        if (i < E) {
            const unsigned s = is64 ? idxw[2 * i] : idxw[i];
            const unsigned d = is64 ? idxw[2 * (E + i)] : idxw[E + i];
            v = make_uint2(s << 7, d << 7);
        }
        idx2[i] = v;
    }
}

// ---------------------------------------------------------------------------
// Wf: fragment-linear weight layout (proven r10). Logical W_col[c][k]:
//   k<128 : c<128 ? w1[k][c] : w1[128+k][c-128]
//   k=128 : +-w1[256][cc]  (-: P, +: Q)   k=129 : +-w1[257][cc]
//   k=130 : b1 (Q only)                   k>130 : 0
// ---------------------------------------------------------------------------
__global__ __launch_bounds__(256) void w1_prep2(const float* __restrict__ w1,
                                                const float* __restrict__ b1,
                                                unsigned short* __restrict__ Wf) {
    const int gid = blockIdx.x * 256 + threadIdx.x;  // 0..5119
    if (gid >= 4 * 5 * 4 * 64) return;
    const int lane = gid & 63;
    const int seg  = gid >> 6;
    const int m    = seg & 3;
    const int ks   = (seg >> 2) % 5;
    const int w    = seg / 20;
    const int c    = w * 64 + m * 16 + (lane & 15);
    const int k0   = ks * 32 + (lane >> 4) * 8;
    const bool isQ = c >= 128;
    const int cc   = c & 127;
    const float sgn = isQ ? 1.f : -1.f;
    unsigned int out[4];
#pragma unroll
    for (int h = 0; h < 4; ++h) {
        float v[2];
#pragma unroll
        for (int j = 0; j < 2; ++j) {
            const int k = k0 + 2 * h + j;
            float x;
            if (k < 128)       x = isQ ? w1[(size_t)(128 + k) * CH + cc]
                                       : w1[(size_t)k * CH + cc];
            else if (k == 128) x = sgn * w1[(size_t)(2 * CH) * CH + cc];
            else if (k == 129) x = sgn * w1[(size_t)(2 * CH + 1) * CH + cc];
            else if (k == 130) x = isQ ? b1[cc] : 0.f;
            else               x = 0.f;
            v[j] = x;
        }
        out[h] = pack2bf(v[0], v[1]);
    }
    *(uint4*)&Wf[(size_t)gid * 8] = make_uint4(out[0], out[1], out[2], out[3]);
}

// ---------------------------------------------------------------------------
// Node stage (r10 structure): 32 nodes x 256 cols, swapped-operand MFMA,
// K=160 (coords+bias folded). Output goes to 4 split half-buffers:
//   wave 0 -> Plo (ch 0-63), 1 -> Phi (64-127), 2 -> Qlo, 3 -> Qhi,
// each [N][64] bf16 (128B rows). c>>6 == wid, so dst is wave-uniform.
// ---------------------------------------------------------------------------
__global__ __launch_bounds__(256) void node_mfma5(
    const float* __restrict__ tokens, const float* __restrict__ coords,
    const unsigned short* __restrict__ Wf, unsigned short* __restrict__ Plo,
    unsigned short* __restrict__ Phi, unsigned short* __restrict__ Qlo,
    unsigned short* __restrict__ Qhi, int N) {
    __shared__ unsigned short Atile[32 * KPAD];  // 12 KB, XOR-swizzled rows

    const int t    = threadIdx.x;
    const int l    = t & 63;
    const int wid  = t >> 6;
    const int n0   = blockIdx.x * 32;
    const int bl   = l & 15;
    const int bh   = l >> 4;

    // token chunks: 32 nodes x 16 chunks of 16B
#pragma unroll
    for (int it = 0; it < 2; ++it) {
        const int idx  = it * 256 + t;
        const int node = idx >> 4;
        const int cq   = idx & 15;
        float4 v0 = make_float4(0.f, 0.f, 0.f, 0.f);
        float4 v1 = v0;
        if (n0 + node < N) {
            const float* src = &tokens[(size_t)(n0 + node) * CH + cq * 8];
            v0 = *(const float4*)src;
            v1 = *(const float4*)(src + 4);
        }
        uint4 u;
        u.x = pack2bf(v0.x, v0.y);
        u.y = pack2bf(v0.z, v0.w);
        u.z = pack2bf(v1.x, v1.y);
        u.w = pack2bf(v1.z, v1.w);
        const int byte = node * 384 + ((cq * 16) ^ ((node & 7) << 4));
        *(uint4*)((char*)Atile + byte) = u;
    }
    // ext chunks: k=128..191 -> (cx, cy, 1, 0, ...)
    {
        const int node = t >> 3;
        const int ce   = t & 7;
        uint4 u = make_uint4(0u, 0u, 0u, 0u);
        if (ce == 0 && n0 + node < N) {
            const float cx = coords[2 * (n0 + node)];
            const float cy = coords[2 * (n0 + node) + 1];
            u.x = pack2bf(cx, cy);
            u.y = pack2bf(1.f, 0.f);
        }
        const int byte = node * 384 + (((16 + ce) * 16) ^ ((node & 7) << 4));
        *(uint4*)((char*)Atile + byte) = u;
    }
    __syncthreads();

    f32x4 acc[4][2];
#pragma unroll
    for (int m = 0; m < 4; ++m)
#pragma unroll
        for (int n = 0; n < 2; ++n) acc[m][n] = (f32x4){0.f, 0.f, 0.f, 0.f};

#pragma unroll
    for (int ks = 0; ks < 5; ++ks) {
        bf16x8 wfrag[4], tfrag[2];
#pragma unroll
        for (int m = 0; m < 4; ++m)
            wfrag[m] = *(const bf16x8*)&Wf[(size_t)(((wid * 5 + ks) * 4 + m) * 64
                                                    + l) * 8];
#pragma unroll
        for (int n = 0; n < 2; ++n) {
            const int row  = n * 16 + bl;
            const int byte = row * 384 + ((ks * 64 + bh * 16) ^ ((row & 7) << 4));
            tfrag[n] = *(const bf16x8*)((const char*)Atile + byte);
        }
#pragma unroll
        for (int m = 0; m < 4; ++m)
#pragma unroll
            for (int n = 0; n < 2; ++n)
                acc[m][n] = __builtin_amdgcn_mfma_f32_16x16x32_bf16(
                    wfrag[m], tfrag[n], acc[m][n], 0, 0, 0);
    }

    // stores: D rows = output cols; c>>6 == wid -> wave-uniform buffer
    unsigned short* dst = (wid == 0) ? Plo : (wid == 1) ? Phi
                          : (wid == 2) ? Qlo : Qhi;
#pragma unroll
    for (int m = 0; m < 4; ++m) {
        const int col = m * 16 + bh * 4;     // 0..60 within the half
#pragma unroll
        for (int n = 0; n < 2; ++n) {
            const int node = n0 + n * 16 + bl;
            if (node < N) {
                uint2 val;
                val.x = pack2bf(acc[m][n][0], acc[m][n][1]);
                val.y = pack2bf(acc[m][n][2], acc[m][n][3]);
                *(uint2*)&dst[(size_t)node * 64 + col] = val;
            }
        }
    }
}

// ---------------------------------------------------------------------------
// Edge pass over one channel half (64 ch, 128B rows). 8-lane group owns 4
// consecutive edges/iter: 8 gathers of uint4 (8 lanes x 16B = one full row)
// -> per-pass working set 12.8 MB (fits aggregate L2 far better than 25.6).
// Pass 0 stores fp32 partials (nontemporal); pass 1 adds + bias -> out.
// ---------------------------------------------------------------------------
template <int PASS>
__global__ __launch_bounds__(256) void edge_pass(
    const unsigned int* __restrict__ idx2w, const unsigned short* __restrict__ Pb,
    const unsigned short* __restrict__ Qb, const float* __restrict__ w2,
    const float* __restrict__ b2, float* __restrict__ partial,
    float* __restrict__ out, long long E) {
    const int t  = threadIdx.x;
    const int gl = t & 7;
    const long long nq = (E + 3) >> 2;                       // edge quads
    const long long g0 = (long long)blockIdx.x * 32 + (t >> 3);
    const long long ng = (long long)gridDim.x * 32;
    const float4 wa = *(const float4*)&w2[PASS * 64 + gl * 8];
    const float4 wb = *(const float4*)&w2[PASS * 64 + gl * 8 + 4];
    const float bias = b2[0];
    const char* P = (const char*)Pb;
    const char* Q = (const char*)Qb;

    for (long long q = g0; q < nq; q += ng) {
        const long long e0 = q << 2;
        const u32x2 iv = __builtin_nontemporal_load(
            (const u32x2*)&idx2w[(e0 + (gl & 3)) * 2]);
        unsigned soff[4], doff[4];
#pragma unroll
        for (int j = 0; j < 4; ++j) {
            soff[j] = __shfl(iv.x, j, 8);
            doff[j] = __shfl(iv.y, j, 8);
        }
        uint4 pv[4], qv[4];
#pragma unroll
        for (int j = 0; j < 4; ++j)
            pv[j] = *(const uint4*)(P + soff[j] + 16 * gl);
#pragma unroll
        for (int j = 0; j < 4; ++j)
            qv[j] = *(const uint4*)(Q + doff[j] + 16 * gl);

        float part[4];
#pragma unroll
        for (int j = 0; j < 4; ++j) {
            const float wv[8] = {wa.x, wa.y, wa.z, wa.w, wb.x, wb.y, wb.z, wb.w};
            const unsigned pw[4] = {pv[j].x, pv[j].y, pv[j].z, pv[j].w};
            const unsigned qw[4] = {qv[j].x, qv[j].y, qv[j].z, qv[j].w};
            float acc = 0.f;
#pragma unroll
            for (int i = 0; i < 4; ++i) {
                const float plo = __uint_as_float(pw[i] << 16);
                const float phi = __uint_as_float(pw[i] & 0xffff0000u);
                const float qlo = __uint_as_float(qw[i] << 16);
                const float qhi = __uint_as_float(qw[i] & 0xffff0000u);
                acc = fmaf(fmaxf(plo + qlo, 0.f), wv[2 * i], acc);
                acc = fmaf(fmaxf(phi + qhi, 0.f), wv[2 * i + 1], acc);
            }
            part[j] = acc;
        }

        // width-8 butterfly with packing; lane gl<4 ends with edge gl's sum
        float t0 = part[0] + __shfl_xor(part[0], 1);
        float t1 = part[1] + __shfl_xor(part[1], 1);
        float t2 = part[2] + __shfl_xor(part[2], 1);
        float t3 = part[3] + __shfl_xor(part[3], 1);
        float a0 = (gl & 1) ? t1 : t0;
        float a1 = (gl & 1) ? t3 : t2;
        a0 += __shfl_xor(a0, 2);
        a1 += __shfl_xor(a1, 2);
        float c = (gl & 2) ? a1 : a0;
        c += __shfl_xor(c, 4);

        const long long e = e0 + gl;
        if (gl < 4 && e < E) {
            if (PASS == 0) {
                __builtin_nontemporal_store(c, &partial[e]);
            } else {
                out[e] = __builtin_nontemporal_load(&partial[e]) + c + bias;
            }
        }
    }
}

extern "C" void kernel_launch(void* const* d_in, const int* in_sizes, int n_in,
                              void* d_out, int out_size, void* d_ws,
                              size_t ws_size, hipStream_t stream) {
    const float* tokens = (const float*)d_in[0];
    const float* coords = (const float*)d_in[1];
    const unsigned int* idxw = (const unsigned int*)d_in[2];
    const float* w1 = (const float*)d_in[3];
    const float* b1 = (const float*)d_in[4];
    const float* w2 = (const float*)d_in[5];
    const float* b2 = (const float*)d_in[6];
    float* out = (float*)d_out;

    const int N = in_sizes[0] / CH;       // 50000
    const long long E = in_sizes[2] / 2;  // 800000
    const long long Epad = ((E + 3) >> 2) << 2;

    unsigned short* Plo = (unsigned short*)d_ws;   // [N][64] each
    unsigned short* Phi = Plo + (size_t)N * 64;
    unsigned short* Qlo = Phi + (size_t)N * 64;
    unsigned short* Qhi = Qlo + (size_t)N * 64;
    uint2* idx2 = (uint2*)(Qhi + (size_t)N * 64);
    unsigned short* Wf = (unsigned short*)(idx2 + Epad);   // 80 KB
    float* partial = (float*)(Wf + 5120 * 8);              // Epad floats

    idx_prep<<<1024, 256, 0, stream>>>(idxw, idx2, E, Epad);
    w1_prep2<<<20, 256, 0, stream>>>(w1, b1, Wf);

    node_mfma5<<<(N + 31) / 32, 256, 0, stream>>>(tokens, coords, Wf,
                                                  Plo, Phi, Qlo, Qhi, N);

    edge_pass<0><<<4096, 256, 0, stream>>>((const unsigned int*)idx2, Plo, Qlo,
                                           w2, b2, partial, out, E);
    edge_pass<1><<<4096, 256, 0, stream>>>((const unsigned int*)idx2, Phi, Qhi,
                                           w2, b2, partial, out, E);
}